// Round 4
// baseline (924.890 us; speedup 1.0000x reference)
//
#include <hip/hip_runtime.h>
#include <hip/hip_bf16.h>
#include <math.h>

// ---------------------------------------------------------------------------
// CoSADUV_NoTemporal. Round 4: kill the per-step barrier drain in the LSTM.
//   - k_lstm2: raw `s_waitcnt lgkmcnt(0); s_barrier` (no vmcnt drain), gx
//     gate-interleaved so each thread loads 4x dwordx2 per step, 2-deep
//     register ping-pong prefetch.
//   - k_gemm_h epilogue writes gx in [u][G] interleaved column order.
// ---------------------------------------------------------------------------

#define NIMG 8
#define PTOT 38400
#define PADH 136  // h row stride in fp16 elems (16B aligned: 136*2=272)

typedef _Float16 half8 __attribute__((ext_vector_type(8)));
typedef _Float16 half4 __attribute__((ext_vector_type(4)));
typedef float float4v __attribute__((ext_vector_type(4)));
typedef __attribute__((address_space(1))) const void gvoid_t;
typedef __attribute__((address_space(3))) void svoid_t;

__device__ __forceinline__ void gload16(void* s, const void* g) {
  __builtin_amdgcn_global_load_lds((gvoid_t*)g, (svoid_t*)s, 16, 0, 0);
}
// barrier that only waits for LDS ops (leaves global loads/stores in flight)
__device__ __forceinline__ void lds_barrier() {
  __asm__ volatile("s_waitcnt lgkmcnt(0)\n\ts_barrier" ::: "memory");
}

__device__ __forceinline__ float rcp_(float x) { return __builtin_amdgcn_rcpf(x); }
__device__ __forceinline__ float fsig(float x) { return rcp_(1.f + __expf(-x)); }
__device__ __forceinline__ float ftanh_(float x) {
  float e = __expf(-2.f * x);
  return 2.f * rcp_(1.f + e) - 1.f;
}

// ---- small FC: sc1[n,512], scr[n,256] from scene_ctx[n,128] ----------------
__global__ void k_fc(const float* __restrict__ ctx, const float* __restrict__ w1,
                     const float* __restrict__ b1, const float* __restrict__ wr,
                     const float* __restrict__ br, float* __restrict__ sc1,
                     float* __restrict__ scr) {
  int n = blockIdx.x;
  __shared__ float c[128];
  int t = threadIdx.x;  // 768 threads
  if (t < 128) c[t] = ctx[n * 128 + t];
  __syncthreads();
  if (t < 512) {
    float a = b1[t];
    const float* wp = w1 + t * 128;
    for (int k = 0; k < 128; k++) a += wp[k] * c[k];
    sc1[n * 512 + t] = a;
  } else {
    int j = t - 512;
    float a = br[j];
    const float* wp = wr + j * 128;
    for (int k = 0; k < 128; k++) a += wp[k] * c[k];
    scr[n * 256 + j] = a;
  }
}

// ---- pack Whh [2,512,128] f32 -> fp16 B-fragments --------------------------
// layout: [dir][wave 8][G 4][kt 4][lane 64][j 8]; frag element j =
//   B[k = kt*32 + (lane>>4)*8 + j][n = G*128 + w*16 + (lane&15)] = Whh[n][k]
__global__ void k_hfrag(const float* __restrict__ whh, _Float16* __restrict__ out) {
  int idx = blockIdx.x * 512 + threadIdx.x;  // 0..131071
  int j = idx & 7, lane = (idx >> 3) & 63, kt = (idx >> 9) & 3;
  int G = (idx >> 11) & 3, w = (idx >> 13) & 7, dir = idx >> 16;
  int n = G * 128 + w * 16 + (lane & 15);
  int k = kt * 32 + (lane >> 4) * 8 + j;
  out[idx] = (_Float16)whh[(dir * 512 + n) * 128 + k];
}

// ---- pack Wih f32 [1024,K] -> fp16 -----------------------------------------
__global__ void k_wpack(const float* __restrict__ in, _Float16* __restrict__ out, int n) {
  int i = blockIdx.x * 512 + threadIdx.x;
  if (i < n) out[i] = (_Float16)in[i];
}

// ---- prep layer 1: local_feats [8,512,60,80] -> x fp16 [8,60,80,512] -------
__global__ void k_prep1(const float* __restrict__ lf, const float* __restrict__ sc1,
                        _Float16* __restrict__ x) {
  __shared__ float tile[32][33];
  int n = blockIdx.z;
  int p0 = blockIdx.x * 32;  // position in 4800
  int i0 = blockIdx.y * 32;  // channel
  const float* src = lf + (size_t)n * 512 * 4800;
  for (int r = threadIdx.y; r < 32; r += 8)
    tile[r][threadIdx.x] = src[(size_t)(i0 + r) * 4800 + p0 + threadIdx.x];
  __syncthreads();
  for (int r = threadIdx.y; r < 32; r += 8) {
    int p = p0 + r;
    int w = p % 80;
    int ch = i0 + threadIdx.x;
    float v = tile[threadIdx.x][r];
    if (w == 0 || w == 79) v += sc1[n * 512 + ch];
    x[((size_t)n * 4800 + p) * 512 + ch] = (_Float16)v;
  }
}

// ---- swap prep: y fp16 [n,A,B,256] -> x fp16 [n,B,A,256] (+scr at a edges) -
__global__ void k_swap(const _Float16* __restrict__ y, const float* __restrict__ sc,
                       _Float16* __restrict__ x, int A, int B) {
  int b = blockIdx.x, a = blockIdx.y, n = blockIdx.z, c = threadIdx.x;
  float v = (float)y[(((size_t)n * A + a) * B + b) * 256 + c];
  if (a == 0 || a == A - 1) v += sc[n * 256 + c];
  x[(((size_t)n * B + b) * A + a) * 256 + c] = (_Float16)v;
}

// ---- fp16 MFMA GEMM: C[M,1024] = A[M,K] * W[1024,K]^T + bias ---------------
// grid (M/128, 8), block 256 = 4 waves (2x2 of 64x64), BK=32.
// Output column order is gate-interleaved: col' = dir*512 + u*4 + G
//   (original col n: dir=n>>9, G=(n>>7)&3, u=n&127)
__global__ __launch_bounds__(256) void k_gemm_h(const _Float16* __restrict__ A,
                                                const _Float16* __restrict__ W,
                                                const float* __restrict__ bias,
                                                _Float16* __restrict__ C, int K) {
  __shared__ _Float16 As[128 * 32];
  __shared__ _Float16 Bs[128 * 32];
  int bm = blockIdx.x * 128, bn = blockIdx.y * 128;
  int tid = threadIdx.x;
  int w = tid >> 6, lane = tid & 63;
  int ln = lane & 15, quad = lane >> 4;
  int Wm = (w >> 1) * 64, Wn = (w & 1) * 64;
  int srow = w * 16 + (lane >> 2);   // staging row within a 64-row half
  int scol = (lane & 3) * 8;         // k-offset (8 halves = 16 B)
  const _Float16* Ap0 = A + (size_t)(bm + srow) * K + scol;
  const _Float16* Ap1 = A + (size_t)(bm + 64 + srow) * K + scol;
  const _Float16* Bp0 = W + (size_t)(bn + srow) * K + scol;
  const _Float16* Bp1 = W + (size_t)(bn + 64 + srow) * K + scol;
  _Float16* sA0 = As + (w * 16) * 32;
  _Float16* sA1 = As + (64 + w * 16) * 32;
  _Float16* sB0 = Bs + (w * 16) * 32;
  _Float16* sB1 = Bs + (64 + w * 16) * 32;

  float4v acc[4][4];
#pragma unroll
  for (int i = 0; i < 4; i++)
#pragma unroll
    for (int j = 0; j < 4; j++) acc[i][j] = (float4v){0.f, 0.f, 0.f, 0.f};

  for (int k0 = 0; k0 < K; k0 += 32) {
    gload16(sA0, Ap0 + k0);
    gload16(sA1, Ap1 + k0);
    gload16(sB0, Bp0 + k0);
    gload16(sB1, Bp1 + k0);
    __syncthreads();
    const _Float16* ar = As + (Wm + ln) * 32 + quad * 8;
    const _Float16* br = Bs + (Wn + ln) * 32 + quad * 8;
    half8 af[4], bf_[4];
#pragma unroll
    for (int mt = 0; mt < 4; mt++) af[mt] = *(const half8*)(ar + mt * 512);
#pragma unroll
    for (int nt = 0; nt < 4; nt++) bf_[nt] = *(const half8*)(br + nt * 512);
#pragma unroll
    for (int mt = 0; mt < 4; mt++)
#pragma unroll
      for (int nt = 0; nt < 4; nt++)
        acc[mt][nt] = __builtin_amdgcn_mfma_f32_16x16x32_f16(af[mt], bf_[nt],
                                                             acc[mt][nt], 0, 0, 0);
    __syncthreads();
  }
#pragma unroll
  for (int nt = 0; nt < 4; nt++) {
    int col = bn + Wn + nt * 16 + ln;     // original gate column n
    int g = col & 511;
    int colp = (col & 512) + (g & 127) * 4 + (g >> 7);  // interleaved
    float bv = bias[col];
#pragma unroll
    for (int mt = 0; mt < 4; mt++) {
      size_t rbase = (size_t)(bm + Wm + mt * 16 + quad * 4) * 1024 + colp;
#pragma unroll
      for (int r = 0; r < 4; r++)
        C[rbase + (size_t)r * 1024] = (_Float16)(acc[mt][nt][r] + bv);
    }
  }
}

// ---- LSTM step body --------------------------------------------------------
__device__ __forceinline__ void lstm_step(const half4* g, const half8 bfrag[4][4],
                                          const _Float16* hread, _Float16* hwrite,
                                          _Float16* yp, size_t yrstride,
                                          float* c, int ln, int quad, int u) {
  half8 af[4];
  const _Float16* hp = hread + ln * PADH + quad * 8;
#pragma unroll
  for (int kt = 0; kt < 4; kt++) af[kt] = *(const half8*)(hp + kt * 32);
  float4v acc[4];
#pragma unroll
  for (int G = 0; G < 4; G++) {
    float4v a = {(float)g[0][G], (float)g[1][G], (float)g[2][G], (float)g[3][G]};
#pragma unroll
    for (int kt = 0; kt < 4; kt++)
      a = __builtin_amdgcn_mfma_f32_16x16x32_f16(af[kt], bfrag[G][kt], a, 0, 0, 0);
    acc[G] = a;
  }
#pragma unroll
  for (int r = 0; r < 4; r++) {
    float iv = fsig(acc[0][r]);
    float fv = fsig(acc[1][r]);
    float gv = ftanh_(acc[2][r]);
    float ov = fsig(acc[3][r]);
    c[r] = fv * c[r] + iv * gv;
    float hv = ov * ftanh_(c[r]);
    hwrite[(quad * 4 + r) * PADH + u] = (_Float16)hv;
    yp[r * yrstride] = (_Float16)hv;
  }
  lds_barrier();
}

// ---- fp16 MFMA BiLSTM recurrence -------------------------------------------
// gx: fp16 [Bq, T, 1024] gate-interleaved (dir*512 + u*4 + G)
// y:  fp16 [Bq, T, 256]; grid (Bq/16, 2), block 512 = 8 waves
__global__ __launch_bounds__(512, 2) void k_lstm2(const _Float16* __restrict__ gx,
                                                  const _Float16* __restrict__ bfr,
                                                  _Float16* __restrict__ y, int T) {
  int dir = blockIdx.y;
  int s0 = blockIdx.x * 16;
  int tid = threadIdx.x;
  int w = tid >> 6;
  int lane = tid & 63;
  int ln = lane & 15, quad = lane >> 4;
  int u = w * 16 + ln;  // unit 0..127 owned by this lane

  __shared__ __align__(16) _Float16 hbuf[2][16 * PADH];

  // resident B-fragments: bfrag[G][kt]
  half8 bfrag[4][4];
  const _Float16* bp = bfr + ((size_t)dir * 8 + w) * 8192;
#pragma unroll
  for (int G = 0; G < 4; G++)
#pragma unroll
    for (int kt = 0; kt < 4; kt++)
      bfrag[G][kt] = *(const half8*)(bp + ((G * 4 + kt) * 64 + lane) * 8);

  for (int i = tid; i < 16 * PADH; i += 512) hbuf[0][i] = (_Float16)0.f;

  float c[4] = {0.f, 0.f, 0.f, 0.f};
  const _Float16* gbase = gx + ((size_t)(s0 + quad * 4) * T) * 1024 + dir * 512 + u * 4;
  size_t sstride = (size_t)T * 1024;
  size_t ystride = (size_t)T * 256;

  half4 gA[4], gB[4];
  {
    int t0 = dir ? (T - 1) : 0;
#pragma unroll
    for (int r = 0; r < 4; r++)
      gA[r] = *(const half4*)(gbase + r * sstride + (size_t)t0 * 1024);
  }
  lds_barrier();

  for (int st = 0; st < T; st += 2) {
    int t = dir ? (T - 1 - st) : st;
    int t1 = dir ? (T - 2 - st) : st + 1;
#pragma unroll
    for (int r = 0; r < 4; r++)
      gB[r] = *(const half4*)(gbase + r * sstride + (size_t)t1 * 1024);
    lstm_step(gA, bfrag, hbuf[0], hbuf[1],
              y + ((size_t)(s0 + quad * 4) * T + t) * 256 + dir * 128 + u,
              ystride, c, ln, quad, u);
    if (st + 2 < T) {
      int t2 = dir ? (T - 3 - st) : st + 2;
#pragma unroll
      for (int r = 0; r < 4; r++)
        gA[r] = *(const half4*)(gbase + r * sstride + (size_t)t2 * 1024);
    }
    lstm_step(gB, bfrag, hbuf[1], hbuf[0],
              y + ((size_t)(s0 + quad * 4) * T + t1) * 256 + dir * 128 + u,
              ystride, c, ln, quad, u);
  }
}

// ---- head: 1x1 conv + sigmoid. y4 in [n, w, h, 256] fp16 layout ------------
__global__ void k_head(const _Float16* __restrict__ y, const float* __restrict__ cw,
                       const float* __restrict__ cb, float* __restrict__ score) {
  int wv = threadIdx.x >> 6, ln = threadIdx.x & 63;
  int o = blockIdx.x * 4 + wv;  // o = (n*80 + w)*60 + h
  const _Float16* yp = y + (size_t)o * 256;
  float a = 0.f;
  for (int c = ln; c < 256; c += 64) a += (float)yp[c] * cw[c];
  for (int off = 32; off; off >>= 1) a += __shfl_down(a, off);
  if (ln == 0) {
    int h = o % 60;
    int nw = o / 60;
    int w = nw % 80;
    int n = nw / 80;
    score[(n * 60 + h) * 80 + w] = fsig(a + cb[0]);
  }
}

// ---- bilinear upsample (align_corners=True) 60x80 -> 480x640 ---------------
__global__ void k_up(const float* __restrict__ score, float* __restrict__ out) {
  int idx = blockIdx.x * 256 + threadIdx.x;
  if (idx >= NIMG * 480 * 640) return;
  int ox = idx % 640;
  int t = idx / 640;
  int oy = t % 480;
  int n = t / 480;
  float sy = oy * (59.f / 479.f);
  float sx = ox * (79.f / 639.f);
  int y0 = min((int)sy, 58);
  int x0 = min((int)sx, 78);
  float ty = sy - (float)y0;
  float tx = sx - (float)x0;
  const float* sp = score + n * 4800;
  float v00 = sp[y0 * 80 + x0], v01 = sp[y0 * 80 + x0 + 1];
  float v10 = sp[(y0 + 1) * 80 + x0], v11 = sp[(y0 + 1) * 80 + x0 + 1];
  float v0 = v00 + (v01 - v00) * tx;
  float v1 = v10 + (v11 - v10) * tx;
  out[idx] = v0 + (v1 - v0) * ty;
}

extern "C" void kernel_launch(void* const* d_in, const int* in_sizes, int n_in,
                              void* d_out, int out_size, void* d_ws, size_t ws_size,
                              hipStream_t stream) {
  const float* lf    = (const float*)d_in[0];
  const float* ctx   = (const float*)d_in[1];
  const float* fc1w  = (const float*)d_in[2];
  const float* fc1b  = (const float*)d_in[3];
  const float* fcrw  = (const float*)d_in[4];
  const float* fcrb  = (const float*)d_in[5];
  const float* wih[4] = {(const float*)d_in[6], (const float*)d_in[9],
                         (const float*)d_in[12], (const float*)d_in[15]};
  const float* whh[4] = {(const float*)d_in[7], (const float*)d_in[10],
                         (const float*)d_in[13], (const float*)d_in[16]};
  const float* bb[4]  = {(const float*)d_in[8], (const float*)d_in[11],
                         (const float*)d_in[14], (const float*)d_in[17]};
  const float* convw = (const float*)d_in[18];
  const float* convb = (const float*)d_in[19];
  float* out = (float*)d_out;

  // workspace: floats first, then fp16 region (16B-aligned offsets)
  float* ws    = (float*)d_ws;
  float* sc1   = ws;            // 4096
  float* scr   = ws + 4096;     // 2048
  float* score = ws + 6144;     // 38400
  _Float16* hb = (_Float16*)(ws + 44544);
  _Float16* hfr  = hb;                 // 4 * 131072
  _Float16* wpk  = hb + 524288;        // 524288 + 3*262144 = 1310720
  _Float16* xbuf = hb + 1835008;       // 38400*512
  _Float16* gxh  = hb + 21495808;      // 38400*1024
  _Float16* ybuf = hb + 60817408;      // 38400*256
  _Float16* wpkL[4] = {wpk, wpk + 524288, wpk + 786432, wpk + 1048576};

  k_fc<<<NIMG, 768, 0, stream>>>(ctx, fc1w, fc1b, fcrw, fcrb, sc1, scr);
  for (int l = 0; l < 4; l++)
    k_hfrag<<<256, 512, 0, stream>>>(whh[l], hfr + (size_t)l * 131072);
  k_wpack<<<1024, 512, 0, stream>>>(wih[0], wpkL[0], 524288);
  for (int l = 1; l < 4; l++)
    k_wpack<<<512, 512, 0, stream>>>(wih[l], wpkL[l], 262144);
  k_prep1<<<dim3(150, 16, NIMG), dim3(32, 8), 0, stream>>>(lf, sc1, xbuf);

  // layer 1: rows (480 seqs, T=80, K=512)
  k_gemm_h<<<dim3(300, 8), 256, 0, stream>>>(xbuf, wpkL[0], bb[0], gxh, 512);
  k_lstm2<<<dim3(30, 2), 512, 0, stream>>>(gxh, hfr + 0 * 131072, ybuf, 80);

  // layer 2: cols (640 seqs, T=60)
  k_swap<<<dim3(80, 60, NIMG), 256, 0, stream>>>(ybuf, scr, xbuf, 60, 80);
  k_gemm_h<<<dim3(300, 8), 256, 0, stream>>>(xbuf, wpkL[1], bb[1], gxh, 256);
  k_lstm2<<<dim3(40, 2), 512, 0, stream>>>(gxh, hfr + 1 * 131072, ybuf, 60);

  // layer 3: rows (480 seqs, T=80)
  k_swap<<<dim3(60, 80, NIMG), 256, 0, stream>>>(ybuf, scr, xbuf, 80, 60);
  k_gemm_h<<<dim3(300, 8), 256, 0, stream>>>(xbuf, wpkL[2], bb[2], gxh, 256);
  k_lstm2<<<dim3(30, 2), 512, 0, stream>>>(gxh, hfr + 2 * 131072, ybuf, 80);

  // layer 4: cols (640 seqs, T=60)
  k_swap<<<dim3(80, 60, NIMG), 256, 0, stream>>>(ybuf, scr, xbuf, 60, 80);
  k_gemm_h<<<dim3(300, 8), 256, 0, stream>>>(xbuf, wpkL[3], bb[3], gxh, 256);
  k_lstm2<<<dim3(40, 2), 512, 0, stream>>>(gxh, hfr + 3 * 131072, ybuf, 60);

  // head + upsample
  k_head<<<PTOT / 4, 256, 0, stream>>>(ybuf, convw, convb, score);
  k_up<<<(NIMG * 480 * 640 + 255) / 256, 256, 0, stream>>>(score, out);
}

// Round 5
// 800.908 us; speedup vs baseline: 1.1548x; 1.1548x over previous
//
#include <hip/hip_runtime.h>
#include <hip/hip_bf16.h>
#include <math.h>

// ---------------------------------------------------------------------------
// CoSADUV_NoTemporal. Round 5:
//   - Gate-interleave permutation moved from GEMM epilogue (4x write
//     amplification, WRITE_SIZE 307MB vs 77MB ideal) into the Wih pack
//     (row permutation). GEMM writes are contiguous again.
//   - k_lstm2: 8 seqs/block (2x blocks) to double the CUs carrying the gx
//     stream (was per-CU-BW-bound at 60-80 CUs).
// ---------------------------------------------------------------------------

#define NIMG 8
#define PTOT 38400
#define PADH 136  // h row stride in fp16 elems (16B aligned: 136*2=272)

typedef _Float16 half8 __attribute__((ext_vector_type(8)));
typedef _Float16 half4 __attribute__((ext_vector_type(4)));
typedef float float4v __attribute__((ext_vector_type(4)));
typedef __attribute__((address_space(1))) const void gvoid_t;
typedef __attribute__((address_space(3))) void svoid_t;

__device__ __forceinline__ void gload16(void* s, const void* g) {
  __builtin_amdgcn_global_load_lds((gvoid_t*)g, (svoid_t*)s, 16, 0, 0);
}
// barrier that only waits for LDS ops (leaves global loads/stores in flight)
__device__ __forceinline__ void lds_barrier() {
  __asm__ volatile("s_waitcnt lgkmcnt(0)\n\ts_barrier" ::: "memory");
}

__device__ __forceinline__ float rcp_(float x) { return __builtin_amdgcn_rcpf(x); }
__device__ __forceinline__ float fsig(float x) { return rcp_(1.f + __expf(-x)); }
__device__ __forceinline__ float ftanh_(float x) {
  float e = __expf(-2.f * x);
  return 2.f * rcp_(1.f + e) - 1.f;
}

// ---- small FC: sc1[n,512], scr[n,256] from scene_ctx[n,128] ----------------
__global__ void k_fc(const float* __restrict__ ctx, const float* __restrict__ w1,
                     const float* __restrict__ b1, const float* __restrict__ wr,
                     const float* __restrict__ br, float* __restrict__ sc1,
                     float* __restrict__ scr) {
  int n = blockIdx.x;
  __shared__ float c[128];
  int t = threadIdx.x;  // 768 threads
  if (t < 128) c[t] = ctx[n * 128 + t];
  __syncthreads();
  if (t < 512) {
    float a = b1[t];
    const float* wp = w1 + t * 128;
    for (int k = 0; k < 128; k++) a += wp[k] * c[k];
    sc1[n * 512 + t] = a;
  } else {
    int j = t - 512;
    float a = br[j];
    const float* wp = wr + j * 128;
    for (int k = 0; k < 128; k++) a += wp[k] * c[k];
    scr[n * 256 + j] = a;
  }
}

// ---- pack Whh [2,512,128] f32 -> fp16 B-fragments --------------------------
// layout: [dir][wave 8][G 4][kt 4][lane 64][j 8]; frag element j =
//   B[k = kt*32 + (lane>>4)*8 + j][n = G*128 + w*16 + (lane&15)] = Whh[n][k]
__global__ void k_hfrag(const float* __restrict__ whh, _Float16* __restrict__ out) {
  int idx = blockIdx.x * 512 + threadIdx.x;  // 0..131071
  int j = idx & 7, lane = (idx >> 3) & 63, kt = (idx >> 9) & 3;
  int G = (idx >> 11) & 3, w = (idx >> 13) & 7, dir = idx >> 16;
  int n = G * 128 + w * 16 + (lane & 15);
  int k = kt * 32 + (lane >> 4) * 8 + j;
  out[idx] = (_Float16)whh[(dir * 512 + n) * 128 + k];
}

// ---- pack + row-permute Wih f32 [1024,K] -> fp16 [1024,K] ------------------
// out row n' = in row orig(n'), orig = (n'&512) + (n'&3)*128 + ((n'&511)>>2)
__global__ void k_wpermpack(const float* __restrict__ in, _Float16* __restrict__ out,
                            int K) {
  int idx = blockIdx.x * 512 + threadIdx.x;
  int np = idx / K, k = idx - np * K;
  int orig = (np & 512) + (np & 3) * 128 + ((np & 511) >> 2);
  out[(size_t)np * K + k] = (_Float16)in[(size_t)orig * K + k];
}

// ---- prep layer 1: local_feats [8,512,60,80] -> x fp16 [8,60,80,512] -------
__global__ void k_prep1(const float* __restrict__ lf, const float* __restrict__ sc1,
                        _Float16* __restrict__ x) {
  __shared__ float tile[32][33];
  int n = blockIdx.z;
  int p0 = blockIdx.x * 32;  // position in 4800
  int i0 = blockIdx.y * 32;  // channel
  const float* src = lf + (size_t)n * 512 * 4800;
  for (int r = threadIdx.y; r < 32; r += 8)
    tile[r][threadIdx.x] = src[(size_t)(i0 + r) * 4800 + p0 + threadIdx.x];
  __syncthreads();
  for (int r = threadIdx.y; r < 32; r += 8) {
    int p = p0 + r;
    int w = p % 80;
    int ch = i0 + threadIdx.x;
    float v = tile[threadIdx.x][r];
    if (w == 0 || w == 79) v += sc1[n * 512 + ch];
    x[((size_t)n * 4800 + p) * 512 + ch] = (_Float16)v;
  }
}

// ---- swap prep: y fp16 [n,A,B,256] -> x fp16 [n,B,A,256] (+scr at a edges) -
__global__ void k_swap(const _Float16* __restrict__ y, const float* __restrict__ sc,
                       _Float16* __restrict__ x, int A, int B) {
  int b = blockIdx.x, a = blockIdx.y, n = blockIdx.z, c = threadIdx.x;
  float v = (float)y[(((size_t)n * A + a) * B + b) * 256 + c];
  if (a == 0 || a == A - 1) v += sc[n * 256 + c];
  x[(((size_t)n * B + b) * A + a) * 256 + c] = (_Float16)v;
}

// ---- fp16 MFMA GEMM: C[M,1024] = A[M,K] * W'[1024,K]^T + bias --------------
// W' is row-permuted (gate-interleaved) so C's natural column order is the
// interleaved gx layout; writes are contiguous. bias indexed via inverse perm.
// grid (M/128, 8), block 256 = 4 waves (2x2 of 64x64), BK=32.
__global__ __launch_bounds__(256) void k_gemm_h(const _Float16* __restrict__ A,
                                                const _Float16* __restrict__ W,
                                                const float* __restrict__ bias,
                                                _Float16* __restrict__ C, int K) {
  __shared__ _Float16 As[128 * 32];
  __shared__ _Float16 Bs[128 * 32];
  int bm = blockIdx.x * 128, bn = blockIdx.y * 128;
  int tid = threadIdx.x;
  int w = tid >> 6, lane = tid & 63;
  int ln = lane & 15, quad = lane >> 4;
  int Wm = (w >> 1) * 64, Wn = (w & 1) * 64;
  int srow = w * 16 + (lane >> 2);   // staging row within a 64-row half
  int scol = (lane & 3) * 8;         // k-offset (8 halves = 16 B)
  const _Float16* Ap0 = A + (size_t)(bm + srow) * K + scol;
  const _Float16* Ap1 = A + (size_t)(bm + 64 + srow) * K + scol;
  const _Float16* Bp0 = W + (size_t)(bn + srow) * K + scol;
  const _Float16* Bp1 = W + (size_t)(bn + 64 + srow) * K + scol;
  _Float16* sA0 = As + (w * 16) * 32;
  _Float16* sA1 = As + (64 + w * 16) * 32;
  _Float16* sB0 = Bs + (w * 16) * 32;
  _Float16* sB1 = Bs + (64 + w * 16) * 32;

  float4v acc[4][4];
#pragma unroll
  for (int i = 0; i < 4; i++)
#pragma unroll
    for (int j = 0; j < 4; j++) acc[i][j] = (float4v){0.f, 0.f, 0.f, 0.f};

  for (int k0 = 0; k0 < K; k0 += 32) {
    gload16(sA0, Ap0 + k0);
    gload16(sA1, Ap1 + k0);
    gload16(sB0, Bp0 + k0);
    gload16(sB1, Bp1 + k0);
    __syncthreads();
    const _Float16* ar = As + (Wm + ln) * 32 + quad * 8;
    const _Float16* br = Bs + (Wn + ln) * 32 + quad * 8;
    half8 af[4], bf_[4];
#pragma unroll
    for (int mt = 0; mt < 4; mt++) af[mt] = *(const half8*)(ar + mt * 512);
#pragma unroll
    for (int nt = 0; nt < 4; nt++) bf_[nt] = *(const half8*)(br + nt * 512);
#pragma unroll
    for (int mt = 0; mt < 4; mt++)
#pragma unroll
      for (int nt = 0; nt < 4; nt++)
        acc[mt][nt] = __builtin_amdgcn_mfma_f32_16x16x32_f16(af[mt], bf_[nt],
                                                             acc[mt][nt], 0, 0, 0);
    __syncthreads();
  }
#pragma unroll
  for (int nt = 0; nt < 4; nt++) {
    int col = bn + Wn + nt * 16 + ln;  // permuted (interleaved) column
    int orig = (col & 512) + (col & 3) * 128 + ((col & 511) >> 2);
    float bv = bias[orig];
#pragma unroll
    for (int mt = 0; mt < 4; mt++) {
      size_t rbase = (size_t)(bm + Wm + mt * 16 + quad * 4) * 1024 + col;
#pragma unroll
      for (int r = 0; r < 4; r++)
        C[rbase + (size_t)r * 1024] = (_Float16)(acc[mt][nt][r] + bv);
    }
  }
}

// ---- LSTM step body --------------------------------------------------------
__device__ __forceinline__ void lstm_step(const half4* g, const half8 bfrag[4][4],
                                          const _Float16* hread, _Float16* hwrite,
                                          _Float16* yp, size_t yrstride,
                                          float* c, int ln, int quad, int u,
                                          bool act) {
  half8 af[4];
  const _Float16* hp = hread + ln * PADH + quad * 8;
#pragma unroll
  for (int kt = 0; kt < 4; kt++) af[kt] = *(const half8*)(hp + kt * 32);
  float4v acc[4];
#pragma unroll
  for (int G = 0; G < 4; G++) {
    float4v a = {(float)g[0][G], (float)g[1][G], (float)g[2][G], (float)g[3][G]};
#pragma unroll
    for (int kt = 0; kt < 4; kt++)
      a = __builtin_amdgcn_mfma_f32_16x16x32_f16(af[kt], bfrag[G][kt], a, 0, 0, 0);
    acc[G] = a;
  }
#pragma unroll
  for (int r = 0; r < 4; r++) {
    float iv = fsig(acc[0][r]);
    float fv = fsig(acc[1][r]);
    float gv = ftanh_(acc[2][r]);
    float ov = fsig(acc[3][r]);
    c[r] = fv * c[r] + iv * gv;
    float hv = ov * ftanh_(c[r]);
    if (act) {
      hwrite[(quad * 4 + r) * PADH + u] = (_Float16)hv;
      yp[r * yrstride] = (_Float16)hv;
    }
  }
  lds_barrier();
}

// ---- fp16 MFMA BiLSTM recurrence -------------------------------------------
// gx: fp16 [Bq, T, 1024] gate-interleaved (dir*512 + u*4 + G)
// y:  fp16 [Bq, T, 256]; grid (Bq/8, 2), block 512 = 8 waves, 8 seqs/block
// (M-rows 8..15 of the MFMA are unused; quads 2-3 skip loads/stores so the
//  gx stream bytes per block halve and twice as many CUs carry the stream)
__global__ __launch_bounds__(512, 2) void k_lstm2(const _Float16* __restrict__ gx,
                                                  const _Float16* __restrict__ bfr,
                                                  _Float16* __restrict__ y, int T) {
  int dir = blockIdx.y;
  int s0 = blockIdx.x * 8;
  int tid = threadIdx.x;
  int w = tid >> 6;
  int lane = tid & 63;
  int ln = lane & 15, quad = lane >> 4;
  int u = w * 16 + ln;  // unit 0..127 owned by this lane
  bool act = quad < 2;  // quads 0,1 own seq rows 0..7

  __shared__ __align__(16) _Float16 hbuf[2][16 * PADH];

  // resident B-fragments: bfrag[G][kt]
  half8 bfrag[4][4];
  const _Float16* bp = bfr + ((size_t)dir * 8 + w) * 8192;
#pragma unroll
  for (int G = 0; G < 4; G++)
#pragma unroll
    for (int kt = 0; kt < 4; kt++)
      bfrag[G][kt] = *(const half8*)(bp + ((G * 4 + kt) * 64 + lane) * 8);

  for (int i = tid; i < 2 * 16 * PADH; i += 512) ((_Float16*)hbuf)[i] = (_Float16)0.f;

  float c[4] = {0.f, 0.f, 0.f, 0.f};
  int srow = s0 + quad * 4;  // valid when act
  const _Float16* gbase = gx + ((size_t)(act ? srow : s0) * T) * 1024 + dir * 512 + u * 4;
  size_t sstride = (size_t)T * 1024;
  size_t ystride = (size_t)T * 256;

  half4 gA[4] = {}, gB[4] = {};
  {
    int t0 = dir ? (T - 1) : 0;
    if (act)
#pragma unroll
      for (int r = 0; r < 4; r++)
        gA[r] = *(const half4*)(gbase + r * sstride + (size_t)t0 * 1024);
  }
  lds_barrier();

  for (int st = 0; st < T; st += 2) {
    int t = dir ? (T - 1 - st) : st;
    int t1 = dir ? (T - 2 - st) : st + 1;
    if (act)
#pragma unroll
      for (int r = 0; r < 4; r++)
        gB[r] = *(const half4*)(gbase + r * sstride + (size_t)t1 * 1024);
    lstm_step(gA, bfrag, hbuf[0], hbuf[1],
              y + ((size_t)(act ? srow : s0) * T + t) * 256 + dir * 128 + u,
              ystride, c, ln, quad, u, act);
    if (st + 2 < T && act) {
      int t2 = dir ? (T - 3 - st) : st + 2;
#pragma unroll
      for (int r = 0; r < 4; r++)
        gA[r] = *(const half4*)(gbase + r * sstride + (size_t)t2 * 1024);
    }
    lstm_step(gB, bfrag, hbuf[1], hbuf[0],
              y + ((size_t)(act ? srow : s0) * T + t1) * 256 + dir * 128 + u,
              ystride, c, ln, quad, u, act);
  }
}

// ---- head: 1x1 conv + sigmoid. y4 in [n, w, h, 256] fp16 layout ------------
__global__ void k_head(const _Float16* __restrict__ y, const float* __restrict__ cw,
                       const float* __restrict__ cb, float* __restrict__ score) {
  int wv = threadIdx.x >> 6, ln = threadIdx.x & 63;
  int o = blockIdx.x * 4 + wv;  // o = (n*80 + w)*60 + h
  const _Float16* yp = y + (size_t)o * 256;
  float a = 0.f;
  for (int c = ln; c < 256; c += 64) a += (float)yp[c] * cw[c];
  for (int off = 32; off; off >>= 1) a += __shfl_down(a, off);
  if (ln == 0) {
    int h = o % 60;
    int nw = o / 60;
    int w = nw % 80;
    int n = nw / 80;
    score[(n * 60 + h) * 80 + w] = fsig(a + cb[0]);
  }
}

// ---- bilinear upsample (align_corners=True) 60x80 -> 480x640 ---------------
__global__ void k_up(const float* __restrict__ score, float* __restrict__ out) {
  int idx = blockIdx.x * 256 + threadIdx.x;
  if (idx >= NIMG * 480 * 640) return;
  int ox = idx % 640;
  int t = idx / 640;
  int oy = t % 480;
  int n = t / 480;
  float sy = oy * (59.f / 479.f);
  float sx = ox * (79.f / 639.f);
  int y0 = min((int)sy, 58);
  int x0 = min((int)sx, 78);
  float ty = sy - (float)y0;
  float tx = sx - (float)x0;
  const float* sp = score + n * 4800;
  float v00 = sp[y0 * 80 + x0], v01 = sp[y0 * 80 + x0 + 1];
  float v10 = sp[(y0 + 1) * 80 + x0], v11 = sp[(y0 + 1) * 80 + x0 + 1];
  float v0 = v00 + (v01 - v00) * tx;
  float v1 = v10 + (v11 - v10) * tx;
  out[idx] = v0 + (v1 - v0) * ty;
}

extern "C" void kernel_launch(void* const* d_in, const int* in_sizes, int n_in,
                              void* d_out, int out_size, void* d_ws, size_t ws_size,
                              hipStream_t stream) {
  const float* lf    = (const float*)d_in[0];
  const float* ctx   = (const float*)d_in[1];
  const float* fc1w  = (const float*)d_in[2];
  const float* fc1b  = (const float*)d_in[3];
  const float* fcrw  = (const float*)d_in[4];
  const float* fcrb  = (const float*)d_in[5];
  const float* wih[4] = {(const float*)d_in[6], (const float*)d_in[9],
                         (const float*)d_in[12], (const float*)d_in[15]};
  const float* whh[4] = {(const float*)d_in[7], (const float*)d_in[10],
                         (const float*)d_in[13], (const float*)d_in[16]};
  const float* bb[4]  = {(const float*)d_in[8], (const float*)d_in[11],
                         (const float*)d_in[14], (const float*)d_in[17]};
  const float* convw = (const float*)d_in[18];
  const float* convb = (const float*)d_in[19];
  float* out = (float*)d_out;

  // workspace: floats first, then fp16 region (16B-aligned offsets)
  float* ws    = (float*)d_ws;
  float* sc1   = ws;            // 4096
  float* scr   = ws + 4096;     // 2048
  float* score = ws + 6144;     // 38400
  _Float16* hb = (_Float16*)(ws + 44544);
  _Float16* hfr  = hb;                 // 4 * 131072
  _Float16* wpk  = hb + 524288;        // 524288 + 3*262144 = 1310720
  _Float16* xbuf = hb + 1835008;       // 38400*512
  _Float16* gxh  = hb + 21495808;      // 38400*1024
  _Float16* ybuf = hb + 60817408;      // 38400*256
  _Float16* wpkL[4] = {wpk, wpk + 524288, wpk + 786432, wpk + 1048576};

  k_fc<<<NIMG, 768, 0, stream>>>(ctx, fc1w, fc1b, fcrw, fcrb, sc1, scr);
  for (int l = 0; l < 4; l++)
    k_hfrag<<<256, 512, 0, stream>>>(whh[l], hfr + (size_t)l * 131072);
  k_wpermpack<<<1024, 512, 0, stream>>>(wih[0], wpkL[0], 512);
  for (int l = 1; l < 4; l++)
    k_wpermpack<<<512, 512, 0, stream>>>(wih[l], wpkL[l], 256);
  k_prep1<<<dim3(150, 16, NIMG), dim3(32, 8), 0, stream>>>(lf, sc1, xbuf);

  // layer 1: rows (480 seqs, T=80, K=512)
  k_gemm_h<<<dim3(300, 8), 256, 0, stream>>>(xbuf, wpkL[0], bb[0], gxh, 512);
  k_lstm2<<<dim3(60, 2), 512, 0, stream>>>(gxh, hfr + 0 * 131072, ybuf, 80);

  // layer 2: cols (640 seqs, T=60)
  k_swap<<<dim3(80, 60, NIMG), 256, 0, stream>>>(ybuf, scr, xbuf, 60, 80);
  k_gemm_h<<<dim3(300, 8), 256, 0, stream>>>(xbuf, wpkL[1], bb[1], gxh, 256);
  k_lstm2<<<dim3(80, 2), 512, 0, stream>>>(gxh, hfr + 1 * 131072, ybuf, 60);

  // layer 3: rows (480 seqs, T=80)
  k_swap<<<dim3(60, 80, NIMG), 256, 0, stream>>>(ybuf, scr, xbuf, 80, 60);
  k_gemm_h<<<dim3(300, 8), 256, 0, stream>>>(xbuf, wpkL[2], bb[2], gxh, 256);
  k_lstm2<<<dim3(60, 2), 512, 0, stream>>>(gxh, hfr + 2 * 131072, ybuf, 80);

  // layer 4: cols (640 seqs, T=60)
  k_swap<<<dim3(80, 60, NIMG), 256, 0, stream>>>(ybuf, scr, xbuf, 60, 80);
  k_gemm_h<<<dim3(300, 8), 256, 0, stream>>>(xbuf, wpkL[3], bb[3], gxh, 256);
  k_lstm2<<<dim3(80, 2), 512, 0, stream>>>(gxh, hfr + 3 * 131072, ybuf, 60);

  // head + upsample
  k_head<<<PTOT / 4, 256, 0, stream>>>(ybuf, convw, convb, score);
  k_up<<<(NIMG * 480 * 640 + 255) / 256, 256, 0, stream>>>(score, out);
}